// Round 1
// baseline (200.539 us; speedup 1.0000x reference)
//
#include <hip/hip_runtime.h>

typedef __attribute__((ext_vector_type(8))) short short8;
typedef __attribute__((ext_vector_type(4))) float floatx4;

#define NTYPES    64
#define WT_STRIDE 5632   // ushorts per type in transposed weight array
#define ROWS_PB   64     // sorted rows per main block
#define THREADS   256    // 4 waves
#define ROW_U     248    // padded ushorts per staged row (496B: stride 121 dwords -> 2-way banks = free)

__device__ __forceinline__ unsigned short f2bf(float f) {
    union { float f; unsigned u; } v; v.f = f;
    unsigned u = v.u;
    u += 0x7FFFu + ((u >> 16) & 1u);   // round-to-nearest-even
    return (unsigned short)(u >> 16);
}

// ---- weight transpose: LDS-staged (coalesced global reads), bf16, scale folded ----
// Layout per type (ushorts, base ty*5632) -- unchanged from previous kernel:
//   irrep0: f in [0,8): [f*512 + r*32 + k2] = W0[i=(f&1)*32+k2][o=(f>>1)*16+r]*s0
//   irrep1: h in [0,2): [4096 + h*512 + r*32 + k] = W1[i=k][o=h*16+r]*s1
//   irrep2:             [5120 + r*32 + k] (k<16 data, k>=16 zero) = W2[i=k][o=r]*s2
__global__ __launch_bounds__(256) void wt_kernel(const float* __restrict__ W0,
                                                 const float* __restrict__ W1,
                                                 const float* __restrict__ W2,
                                                 unsigned short* __restrict__ wt) {
    __shared__ float ws0[4096];
    __shared__ float ws1[1024];
    __shared__ float ws2[256];
    const int t = blockIdx.x, tid = threadIdx.x;
    const float4* s0 = (const float4*)(W0 + (size_t)t * 4096);
#pragma unroll
    for (int j = 0; j < 4; ++j) ((float4*)ws0)[j * 256 + tid] = s0[j * 256 + tid];
    ((float4*)ws1)[tid] = ((const float4*)(W1 + (size_t)t * 1024))[tid];
    if (tid < 64) ((float4*)ws2)[tid] = ((const float4*)(W2 + (size_t)t * 256))[tid];
    __syncthreads();
    unsigned short* dst = wt + (size_t)t * WT_STRIDE;
    for (int e = tid; e < 4096; e += 256) {
        int f = e >> 9, rem = e & 511, rr = rem >> 5, k2 = rem & 31;
        int i = (f & 1) * 32 + k2, o = (f >> 1) * 16 + rr;
        dst[e] = f2bf(ws0[i * 64 + o] * 0.125f);
    }
    for (int e = tid; e < 1024; e += 256) {
        int h = e >> 9, rem = e & 511, rr = rem >> 5, k = rem & 31;
        dst[4096 + e] = f2bf(ws1[k * 32 + h * 16 + rr] * 0.17677669529663687f);
    }
    for (int e = tid; e < 512; e += 256) {
        int rr = e >> 5, k = e & 31;
        dst[5120 + e] = (k < 16) ? f2bf(ws2[k * 16 + rr] * 0.25f) : (unsigned short)0;
    }
}

// ---- global counting sort by type: hist -> scan -> scatter (packed node|ty<<24) ----
__global__ __launch_bounds__(256) void hist_kernel(const int* __restrict__ idx,
                                                   int* __restrict__ bh, int n) {
    __shared__ int c[NTYPES];
    const int b = blockIdx.x, tid = threadIdx.x;
    if (tid < NTYPES) c[tid] = 0;
    __syncthreads();
    int g = b * 256 + tid;
    if (g < n) atomicAdd(&c[idx[g]], 1);
    __syncthreads();
    if (tid < NTYPES) bh[b * NTYPES + tid] = c[tid];
}

__global__ __launch_bounds__(64) void scan_kernel(const int* __restrict__ bh,
                                                  int* __restrict__ obh,
                                                  int* __restrict__ tbase, int nb) {
    __shared__ int tot[NTYPES], pre[NTYPES];
    const int t = threadIdx.x;   // 64 threads
    int run = 0;
    for (int b = 0; b < nb; ++b) {
        int v = bh[b * NTYPES + t];
        obh[b * NTYPES + t] = run;
        run += v;
    }
    tot[t] = run;
    __syncthreads();
    if (t == 0) {
        int a = 0;
        for (int u = 0; u < NTYPES; ++u) { pre[u] = a; a += tot[u]; }
    }
    __syncthreads();
    tbase[t] = pre[t];
}

__global__ __launch_bounds__(256) void scatter_kernel(const int* __restrict__ idx,
                                                      const int* __restrict__ obh,
                                                      const int* __restrict__ tbase,
                                                      int* __restrict__ psort, int n) {
    __shared__ int cur[NTYPES], off[NTYPES];
    const int b = blockIdx.x, tid = threadIdx.x;
    if (tid < NTYPES) { cur[tid] = 0; off[tid] = tbase[tid] + obh[b * NTYPES + tid]; }
    __syncthreads();
    int g = b * 256 + tid;
    if (g < n) {
        int ty = idx[g];
        int rk = atomicAdd(&cur[ty], 1);
        psort[off[ty] + rk] = g | (ty << 24);
    }
}

// ---- main: 64 sorted rows/block; frag-permuted bf16 staging; full 16-row tiles;
// ---- swapped-operand MFMA (D[o][node]) so all C stores are float4.
// LDS row layout (ushort offsets): [0,64) irrep0 i; [64,160) = 64+d*32+i (irrep1,
// d<3,i<32); [160,240) = 160+d*16+i (irrep2, d<5,i<16); [240,248) pad.
__global__ __launch_bounds__(THREADS, 4) void main_kernel(
    const float* __restrict__ x,
    const int* __restrict__ psort,
    const unsigned short* __restrict__ wt,
    float* __restrict__ out, int n)
{
    __shared__ __align__(16) unsigned short xrow[ROWS_PB * ROW_U];  // 31744 B
    __shared__ int pls[ROWS_PB];
    __shared__ int tinfo[ROWS_PB];
    __shared__ int ntiles;

    const int b = blockIdx.x, tid = threadIdx.x;
    const int nbase = b * ROWS_PB;
    const int nv = min(ROWS_PB, n - nbase);
    const int wv = tid >> 6, ln = tid & 63;

    if (tid < ROWS_PB) pls[tid] = (nbase + tid < n) ? psort[nbase + tid] : 0;
    __syncthreads();

    // tile build on wave 0 (segments = runs of equal type in the sorted slice)
    if (wv == 0) {
        int v = (ln < nv) ? (pls[ln] >> 24) : -1;
        int pv = __shfl_up(v, 1);
        bool bnd = (ln < nv) && (ln == 0 || v != pv);
        unsigned long long bm = __ballot(bnd);
        if (ln == 0) {
            int ntl = 0;
            unsigned long long m = bm;
            while (m) {
                unsigned long long m2 = m & (m - 1);
                int s = (int)__builtin_ctzll(m);
                int e = m2 ? (int)__builtin_ctzll(m2) : nv;
                int t = pls[s] >> 24;
                for (int q = s; q < e; q += 16)
                    tinfo[ntl++] = (t << 16) | (q << 8) | min(16, e - q);
                m = m2;
            }
            ntiles = ntl;
        }
    }

    // stage gathered rows -> bf16 LDS, frag-permuted layout (rows read 960B contiguous)
#pragma unroll
    for (int it = 0; it < 15; ++it) {
        int e = it * THREADS + tid;            // 64 rows * 60 float4 = 3840 = 15*256
        int row = e / 60, c4 = e - row * 60;
        if (row < nv) {
            int node = pls[row] & 0xFFFFFF;
            float4 f = *(const float4*)(x + (size_t)node * 240 + c4 * 4);
            unsigned short qq[4] = {f2bf(f.x), f2bf(f.y), f2bf(f.z), f2bf(f.w)};
            unsigned short* xr = xrow + row * ROW_U;
            if (c4 < 16) {
                *(ushort4*)(xr + c4 * 4) = ushort4{qq[0], qq[1], qq[2], qq[3]};
            } else if (c4 < 40) {
                int t0 = c4 * 4 - 64;
                int i = t0 / 3, d = t0 - i * 3;
#pragma unroll
                for (int j = 0; j < 4; ++j) {
                    xr[64 + d * 32 + i] = qq[j];
                    if (++d == 3) { d = 0; ++i; }
                }
            } else {
                int t0 = c4 * 4 - 160;
                int i = t0 / 5, d = t0 - i * 5;
#pragma unroll
                for (int j = 0; j < 4; ++j) {
                    xr[160 + d * 16 + i] = qq[j];
                    if (++d == 5) { d = 0; ++i; }
                }
            }
        }
    }
    __syncthreads();

    const int r = ln & 15, q4 = ln >> 4;
    const int NT = ntiles;

    for (int ti = wv; ti < NT; ti += (THREADS / 64)) {
        const int info = tinfo[ti];
        const int ty = info >> 16, s0 = (info >> 8) & 0xFF, rows = info & 0xFF;
        const int lrow = s0 + min(r, rows - 1);
        const unsigned short* xr = xrow + lrow * ROW_U;
        const unsigned short* wb = wt + (size_t)ty * WT_STRIDE;
        const bool vst = (r < rows);
        const int gnode = vst ? (pls[s0 + r] & 0xFFFFFF) : 0;
        float* op = out + (size_t)gnode * 240;

        // x fragments (B operand: lane&15 = node col, lane>>4 = k group) — all b128
        short8 bx0 = *(const short8*)(xr + q4 * 8);
        short8 bx1 = *(const short8*)(xr + 32 + q4 * 8);

        // ---- irrep0: D[o=nt*16+q4*4+reg][node=r], K=64 ----
#pragma unroll
        for (int nt = 0; nt < 4; ++nt) {
            short8 wa = *(const short8*)(wb + (nt * 2) * 512 + r * 32 + q4 * 8);
            short8 wc = *(const short8*)(wb + (nt * 2 + 1) * 512 + r * 32 + q4 * 8);
            floatx4 ac = {0.f, 0.f, 0.f, 0.f};
            ac = __builtin_amdgcn_mfma_f32_16x16x32_bf16(wa, bx0, ac, 0, 0, 0);
            ac = __builtin_amdgcn_mfma_f32_16x16x32_bf16(wc, bx1, ac, 0, 0, 0);
            if (vst) *(floatx4*)(op + nt * 16 + q4 * 4) = ac;   // 4 consecutive o
        }

        // ---- irrep1: per d, 2 M-tiles; store 12 consecutive floats as 3x float4 ----
        {
            short8 wc0 = *(const short8*)(wb + 4096 + r * 32 + q4 * 8);
            short8 wc1 = *(const short8*)(wb + 4096 + 512 + r * 32 + q4 * 8);
            floatx4 a1[2][3];
#pragma unroll
            for (int d = 0; d < 3; ++d) {
                short8 bx = *(const short8*)(xr + 64 + d * 32 + q4 * 8);
                floatx4 z = {0.f, 0.f, 0.f, 0.f};
                a1[0][d] = __builtin_amdgcn_mfma_f32_16x16x32_bf16(wc0, bx, z, 0, 0, 0);
                a1[1][d] = __builtin_amdgcn_mfma_f32_16x16x32_bf16(wc1, bx, z, 0, 0, 0);
            }
            if (vst) {
#pragma unroll
                for (int h = 0; h < 2; ++h) {
                    float* o1 = op + 64 + (h * 16 + q4 * 4) * 3;
                    floatx4 v0 = {a1[h][0][0], a1[h][1][0], a1[h][2][0], a1[h][0][1]};
                    floatx4 v1 = {a1[h][1][1], a1[h][2][1], a1[h][0][2], a1[h][1][2]};
                    floatx4 v2 = {a1[h][2][2], a1[h][0][3], a1[h][1][3], a1[h][2][3]};
                    *(floatx4*)(o1)     = v0;
                    *(floatx4*)(o1 + 4) = v1;
                    *(floatx4*)(o1 + 8) = v2;
                }
            }
        }

        // ---- irrep2: per d, M=16 K=16 (w-side zero-padded to K=32); 5x float4 store ----
        {
            short8 wc2 = *(const short8*)(wb + 5120 + r * 32 + q4 * 8);
            floatx4 a2[5];
#pragma unroll
            for (int d = 0; d < 5; ++d) {
                // q4>=2 lanes read a clamped (junk but finite) frag; w-side k>=16 is zero
                short8 bx = *(const short8*)(xr + 160 + d * 16 + (q4 & 1) * 8);
                floatx4 z = {0.f, 0.f, 0.f, 0.f};
                a2[d] = __builtin_amdgcn_mfma_f32_16x16x32_bf16(wc2, bx, z, 0, 0, 0);
            }
            if (vst) {
                float* o2 = op + 160 + q4 * 20;
                floatx4 v0 = {a2[0][0], a2[1][0], a2[2][0], a2[3][0]};
                floatx4 v1 = {a2[4][0], a2[0][1], a2[1][1], a2[2][1]};
                floatx4 v2 = {a2[3][1], a2[4][1], a2[0][2], a2[1][2]};
                floatx4 v3 = {a2[2][2], a2[3][2], a2[4][2], a2[0][3]};
                floatx4 v4 = {a2[1][3], a2[2][3], a2[3][3], a2[4][3]};
                *(floatx4*)(o2)      = v0;
                *(floatx4*)(o2 + 4)  = v1;
                *(floatx4*)(o2 + 8)  = v2;
                *(floatx4*)(o2 + 12) = v3;
                *(floatx4*)(o2 + 16) = v4;
            }
        }
    }
}

extern "C" void kernel_launch(void* const* d_in, const int* in_sizes, int n_in,
                              void* d_out, int out_size, void* d_ws, size_t ws_size,
                              hipStream_t stream) {
    const float* x  = (const float*)d_in[0];
    const float* W0 = (const float*)d_in[1];
    const float* W1 = (const float*)d_in[2];
    const float* W2 = (const float*)d_in[3];
    const int*   idx = (const int*)d_in[4];
    float* out = (float*)d_out;
    const int n = in_sizes[4];                    // 65536 nodes
    const int nb = (n + 255) / 256;

    char* ws = (char*)d_ws;
    unsigned short* wt = (unsigned short*)ws;     // 720896 B
    size_t off = (size_t)NTYPES * WT_STRIDE * 2;
    int* psort = (int*)(ws + off); off += (size_t)n * 4;
    int* bh    = (int*)(ws + off); off += (size_t)nb * NTYPES * 4;
    int* obh   = (int*)(ws + off); off += (size_t)nb * NTYPES * 4;
    int* tbase = (int*)(ws + off);

    wt_kernel     <<<NTYPES, 256, 0, stream>>>(W0, W1, W2, wt);
    hist_kernel   <<<nb, 256, 0, stream>>>(idx, bh, n);
    scan_kernel   <<<1, 64, 0, stream>>>(bh, obh, tbase, nb);
    scatter_kernel<<<nb, 256, 0, stream>>>(idx, obh, tbase, psort, n);
    main_kernel   <<<(n + ROWS_PB - 1) / ROWS_PB, THREADS, 0, stream>>>(x, psort, wt, out, n);
}

// Round 3
// 148.805 us; speedup vs baseline: 1.3477x; 1.3477x over previous
//
#include <hip/hip_runtime.h>

typedef __attribute__((ext_vector_type(8))) short short8;
typedef __attribute__((ext_vector_type(4))) float floatx4;

#define NTYPES    64
#define WT_STRIDE 5632   // ushorts per type in transposed weight array
#define ROWS_PB   64     // sorted rows per main block
#define THREADS   256    // 4 waves
#define ROW_U     248    // padded ushorts per staged row (496B: stride 121 dwords -> 2-way banks = free)
#define CPAD      16     // counter padding (ints) -> 64B, one cache line per counter

__device__ __forceinline__ unsigned short f2bf(float f) {
    union { float f; unsigned u; } v; v.f = f;
    unsigned u = v.u;
    u += 0x7FFFu + ((u >> 16) & 1u);   // round-to-nearest-even
    return (unsigned short)(u >> 16);
}

// ---- weight transpose: LDS-staged (coalesced global reads), bf16, scale folded ----
// Also zeroes the global type counters (stream-orders before hist_kernel).
// Layout per type (ushorts, base ty*5632):
//   irrep0: f in [0,8): [f*512 + r*32 + k2] = W0[i=(f&1)*32+k2][o=(f>>1)*16+r]*s0
//   irrep1: h in [0,2): [4096 + h*512 + r*32 + k] = W1[i=k][o=h*16+r]*s1
//   irrep2:             [5120 + r*32 + k] (k<16 data, k>=16 zero) = W2[i=k][o=r]*s2
__global__ __launch_bounds__(256) void wt_kernel(const float* __restrict__ W0,
                                                 const float* __restrict__ W1,
                                                 const float* __restrict__ W2,
                                                 unsigned short* __restrict__ wt,
                                                 int* __restrict__ gcount) {
    __shared__ float ws0[4096];
    __shared__ float ws1[1024];
    __shared__ float ws2[256];
    const int t = blockIdx.x, tid = threadIdx.x;
    if (t == 0 && tid < NTYPES) gcount[tid * CPAD] = 0;
    const float4* s0 = (const float4*)(W0 + (size_t)t * 4096);
#pragma unroll
    for (int j = 0; j < 4; ++j) ((float4*)ws0)[j * 256 + tid] = s0[j * 256 + tid];
    ((float4*)ws1)[tid] = ((const float4*)(W1 + (size_t)t * 1024))[tid];
    if (tid < 64) ((float4*)ws2)[tid] = ((const float4*)(W2 + (size_t)t * 256))[tid];
    __syncthreads();
    unsigned short* dst = wt + (size_t)t * WT_STRIDE;
    for (int e = tid; e < 4096; e += 256) {
        int f = e >> 9, rem = e & 511, rr = rem >> 5, k2 = rem & 31;
        int i = (f & 1) * 32 + k2, o = (f >> 1) * 16 + rr;
        dst[e] = f2bf(ws0[i * 64 + o] * 0.125f);
    }
    for (int e = tid; e < 1024; e += 256) {
        int h = e >> 9, rem = e & 511, rr = rem >> 5, k = rem & 31;
        dst[4096 + e] = f2bf(ws1[k * 32 + h * 16 + rr] * 0.17677669529663687f);
    }
    for (int e = tid; e < 512; e += 256) {
        int rr = e >> 5, k = e & 31;
        dst[5120 + e] = (k < 16) ? f2bf(ws2[k * 16 + rr] * 0.25f) : (unsigned short)0;
    }
}

// ---- sort pass 1: per-block LDS histogram -> padded global counters ----
__global__ __launch_bounds__(256) void hist_kernel(const int* __restrict__ idx,
                                                   int* __restrict__ gcount, int n) {
    __shared__ int c[NTYPES];
    const int tid = threadIdx.x, g = blockIdx.x * 256 + tid;
    if (tid < NTYPES) c[tid] = 0;
    __syncthreads();
    if (g < n) atomicAdd(&c[idx[g]], 1);
    __syncthreads();
    if (tid < NTYPES && c[tid]) atomicAdd(&gcount[tid * CPAD], c[tid]);
}

// ---- sort pass 2: one-wave exclusive scan of 64 totals -> global cursors ----
__global__ __launch_bounds__(64) void base_kernel(const int* __restrict__ gcount,
                                                  int* __restrict__ gcur) {
    const int t = threadIdx.x;           // 64 threads = 1 wave
    int v = gcount[t * CPAD];
    int s = v;
#pragma unroll
    for (int o = 1; o < 64; o <<= 1) {
        int u = __shfl_up(s, o);
        if (t >= o) s += u;
    }
    gcur[t * CPAD] = s - v;              // exclusive base
}

// ---- sort pass 3: block reserves a chunk per type, writes packed node|ty<<24 ----
__global__ __launch_bounds__(256) void scatter_kernel(const int* __restrict__ idx,
                                                      int* __restrict__ gcur,
                                                      int* __restrict__ psort, int n) {
    __shared__ int c[NTYPES], off[NTYPES], cur[NTYPES];
    const int tid = threadIdx.x, g = blockIdx.x * 256 + tid;
    if (tid < NTYPES) { c[tid] = 0; cur[tid] = 0; }
    __syncthreads();
    int ty = -1;
    if (g < n) { ty = idx[g]; atomicAdd(&c[ty], 1); }
    __syncthreads();
    if (tid < NTYPES && c[tid]) off[tid] = atomicAdd(&gcur[tid * CPAD], c[tid]);
    __syncthreads();
    if (g < n) {
        int rk = atomicAdd(&cur[ty], 1);
        psort[off[ty] + rk] = g | (ty << 24);
    }
}

// ---- main: 64 sorted rows/block; frag-permuted bf16 staging; full 16-row tiles;
// ---- swapped-operand MFMA (D[o][node]) so all C stores are float4.
// LDS row layout (ushort offsets): [0,64) irrep0 i; [64,160) = 64+d*32+i (irrep1,
// d<3,i<32); [160,240) = 160+d*16+i (irrep2, d<5,i<16); [240,248) pad.
__global__ __launch_bounds__(THREADS, 4) void main_kernel(
    const float* __restrict__ x,
    const int* __restrict__ psort,
    const unsigned short* __restrict__ wt,
    float* __restrict__ out, int n)
{
    __shared__ __align__(16) unsigned short xrow[ROWS_PB * ROW_U];  // 31744 B
    __shared__ int pls[ROWS_PB];
    __shared__ int tinfo[ROWS_PB];
    __shared__ int ntiles;

    const int b = blockIdx.x, tid = threadIdx.x;
    const int nbase = b * ROWS_PB;
    const int nv = min(ROWS_PB, n - nbase);
    const int wv = tid >> 6, ln = tid & 63;

    if (tid < ROWS_PB) pls[tid] = (nbase + tid < n) ? psort[nbase + tid] : 0;
    __syncthreads();

    // tile build on wave 0 (segments = runs of equal type in the sorted slice)
    if (wv == 0) {
        int v = (ln < nv) ? (pls[ln] >> 24) : -1;
        int pv = __shfl_up(v, 1);
        bool bnd = (ln < nv) && (ln == 0 || v != pv);
        unsigned long long bm = __ballot(bnd);
        if (ln == 0) {
            int ntl = 0;
            unsigned long long m = bm;
            while (m) {
                unsigned long long m2 = m & (m - 1);
                int s = (int)__builtin_ctzll(m);
                int e = m2 ? (int)__builtin_ctzll(m2) : nv;
                int t = pls[s] >> 24;
                for (int q = s; q < e; q += 16)
                    tinfo[ntl++] = (t << 16) | (q << 8) | min(16, e - q);
                m = m2;
            }
            ntiles = ntl;
        }
    }

    // stage gathered rows -> bf16 LDS, frag-permuted layout (rows read 960B contiguous)
#pragma unroll
    for (int it = 0; it < 15; ++it) {
        int e = it * THREADS + tid;            // 64 rows * 60 float4 = 3840 = 15*256
        int row = e / 60, c4 = e - row * 60;
        if (row < nv) {
            int node = pls[row] & 0xFFFFFF;
            float4 f = *(const float4*)(x + (size_t)node * 240 + c4 * 4);
            unsigned short qq[4] = {f2bf(f.x), f2bf(f.y), f2bf(f.z), f2bf(f.w)};
            unsigned short* xr = xrow + row * ROW_U;
            if (c4 < 16) {
                *(ushort4*)(xr + c4 * 4) = ushort4{qq[0], qq[1], qq[2], qq[3]};
            } else if (c4 < 40) {
                int t0 = c4 * 4 - 64;
                int i = t0 / 3, d = t0 - i * 3;
#pragma unroll
                for (int j = 0; j < 4; ++j) {
                    xr[64 + d * 32 + i] = qq[j];
                    if (++d == 3) { d = 0; ++i; }
                }
            } else {
                int t0 = c4 * 4 - 160;
                int i = t0 / 5, d = t0 - i * 5;
#pragma unroll
                for (int j = 0; j < 4; ++j) {
                    xr[160 + d * 16 + i] = qq[j];
                    if (++d == 5) { d = 0; ++i; }
                }
            }
        }
    }
    __syncthreads();

    const int r = ln & 15, q4 = ln >> 4;
    const int NT = ntiles;

    for (int ti = wv; ti < NT; ti += (THREADS / 64)) {
        const int info = tinfo[ti];
        const int ty = info >> 16, s0 = (info >> 8) & 0xFF, rows = info & 0xFF;
        const int lrow = s0 + min(r, rows - 1);
        const unsigned short* xr = xrow + lrow * ROW_U;
        const unsigned short* wb = wt + (size_t)ty * WT_STRIDE;
        const bool vst = (r < rows);
        const int gnode = vst ? (pls[s0 + r] & 0xFFFFFF) : 0;
        float* op = out + (size_t)gnode * 240;

        // x fragments (B operand: lane&15 = node col, lane>>4 = k group) — all b128
        short8 bx0 = *(const short8*)(xr + q4 * 8);
        short8 bx1 = *(const short8*)(xr + 32 + q4 * 8);

        // ---- irrep0: D[o=nt*16+q4*4+reg][node=r], K=64 ----
#pragma unroll
        for (int nt = 0; nt < 4; ++nt) {
            short8 wa = *(const short8*)(wb + (nt * 2) * 512 + r * 32 + q4 * 8);
            short8 wc = *(const short8*)(wb + (nt * 2 + 1) * 512 + r * 32 + q4 * 8);
            floatx4 ac = {0.f, 0.f, 0.f, 0.f};
            ac = __builtin_amdgcn_mfma_f32_16x16x32_bf16(wa, bx0, ac, 0, 0, 0);
            ac = __builtin_amdgcn_mfma_f32_16x16x32_bf16(wc, bx1, ac, 0, 0, 0);
            if (vst) *(floatx4*)(op + nt * 16 + q4 * 4) = ac;   // 4 consecutive o
        }

        // ---- irrep1: per d, 2 M-tiles; store 12 consecutive floats as 3x float4 ----
        {
            short8 wc0 = *(const short8*)(wb + 4096 + r * 32 + q4 * 8);
            short8 wc1 = *(const short8*)(wb + 4096 + 512 + r * 32 + q4 * 8);
            floatx4 a1[2][3];
#pragma unroll
            for (int d = 0; d < 3; ++d) {
                short8 bx = *(const short8*)(xr + 64 + d * 32 + q4 * 8);
                floatx4 z = {0.f, 0.f, 0.f, 0.f};
                a1[0][d] = __builtin_amdgcn_mfma_f32_16x16x32_bf16(wc0, bx, z, 0, 0, 0);
                a1[1][d] = __builtin_amdgcn_mfma_f32_16x16x32_bf16(wc1, bx, z, 0, 0, 0);
            }
            if (vst) {
#pragma unroll
                for (int h = 0; h < 2; ++h) {
                    float* o1 = op + 64 + (h * 16 + q4 * 4) * 3;
                    floatx4 v0 = {a1[h][0][0], a1[h][1][0], a1[h][2][0], a1[h][0][1]};
                    floatx4 v1 = {a1[h][1][1], a1[h][2][1], a1[h][0][2], a1[h][1][2]};
                    floatx4 v2 = {a1[h][2][2], a1[h][0][3], a1[h][1][3], a1[h][2][3]};
                    *(floatx4*)(o1)     = v0;
                    *(floatx4*)(o1 + 4) = v1;
                    *(floatx4*)(o1 + 8) = v2;
                }
            }
        }

        // ---- irrep2: per d, M=16 K=16 (w-side zero-padded to K=32); 5x float4 store ----
        {
            short8 wc2 = *(const short8*)(wb + 5120 + r * 32 + q4 * 8);
            floatx4 a2[5];
#pragma unroll
            for (int d = 0; d < 5; ++d) {
                // q4>=2 lanes read a clamped (junk but finite) frag; w-side k>=16 is zero
                short8 bx = *(const short8*)(xr + 160 + d * 16 + (q4 & 1) * 8);
                floatx4 z = {0.f, 0.f, 0.f, 0.f};
                a2[d] = __builtin_amdgcn_mfma_f32_16x16x32_bf16(wc2, bx, z, 0, 0, 0);
            }
            if (vst) {
                float* o2 = op + 160 + q4 * 20;
                floatx4 v0 = {a2[0][0], a2[1][0], a2[2][0], a2[3][0]};
                floatx4 v1 = {a2[4][0], a2[0][1], a2[1][1], a2[2][1]};
                floatx4 v2 = {a2[3][1], a2[4][1], a2[0][2], a2[1][2]};
                floatx4 v3 = {a2[2][2], a2[3][2], a2[4][2], a2[0][3]};
                floatx4 v4 = {a2[1][3], a2[2][3], a2[3][3], a2[4][3]};
                *(floatx4*)(o2)      = v0;
                *(floatx4*)(o2 + 4)  = v1;
                *(floatx4*)(o2 + 8)  = v2;
                *(floatx4*)(o2 + 12) = v3;
                *(floatx4*)(o2 + 16) = v4;
            }
        }
    }
}

extern "C" void kernel_launch(void* const* d_in, const int* in_sizes, int n_in,
                              void* d_out, int out_size, void* d_ws, size_t ws_size,
                              hipStream_t stream) {
    const float* x  = (const float*)d_in[0];
    const float* W0 = (const float*)d_in[1];
    const float* W1 = (const float*)d_in[2];
    const float* W2 = (const float*)d_in[3];
    const int*   idx = (const int*)d_in[4];
    float* out = (float*)d_out;
    const int n = in_sizes[4];                    // 65536 nodes
    const int nb = (n + 255) / 256;

    char* ws = (char*)d_ws;
    unsigned short* wt = (unsigned short*)ws;     // 720896 B
    size_t off = (size_t)NTYPES * WT_STRIDE * 2;
    int* psort  = (int*)(ws + off); off += (size_t)n * 4;
    int* gcount = (int*)(ws + off); off += (size_t)NTYPES * CPAD * 4;
    int* gcur   = (int*)(ws + off);

    wt_kernel     <<<NTYPES, 256, 0, stream>>>(W0, W1, W2, wt, gcount);
    hist_kernel   <<<nb, 256, 0, stream>>>(idx, gcount, n);
    base_kernel   <<<1, 64, 0, stream>>>(gcount, gcur);
    scatter_kernel<<<nb, 256, 0, stream>>>(idx, gcur, psort, n);
    main_kernel   <<<(n + ROWS_PB - 1) / ROWS_PB, THREADS, 0, stream>>>(x, psort, wt, out, n);
}